// Round 1
// baseline (1301.334 us; speedup 1.0000x reference)
//
#include <hip/hip_runtime.h>
#include <hip/hip_bf16.h>

// Problem constants (match reference)
#define B_SZ 128
#define K_SZ 65536
#define H_SZ 768
#define TOPK 5
#define NEG_MIN 64512
#define OUTC 64513            // NEG_MIN + 1
#define NBINS 65536
#define INV_T (1.0f/0.07f)

// ---- sortable 16-bit key <-> bf16 value -------------------------------------
// bf16 RNE round, then order-preserving transform: ascending key == ascending value.
__device__ __forceinline__ unsigned f32_key(float v) {
    unsigned u = __float_as_uint(v);
    unsigned r = ((u >> 16) & 1u) + 0x7FFFu;
    unsigned b = (u + r) >> 16;                       // bf16 bits (RNE)
    return (b & 0x8000u) ? (0xFFFFu & ~b) : (b | 0x8000u);
}
__device__ __forceinline__ float key_val(unsigned key) {
    unsigned b = (key & 0x8000u) ? (key ^ 0x8000u) : (0xFFFFu & ~key);
    return __uint_as_float(b << 16);
}

// ---- kernel 1: l2-normalize q ----------------------------------------------
__global__ __launch_bounds__(256) void norm_kernel(const float* __restrict__ q,
                                                   float* __restrict__ qn) {
    __shared__ float red[256];
    const int b = blockIdx.x, t = threadIdx.x;
    float s = 0.f;
    for (int h = t; h < H_SZ; h += 256) { float v = q[b*H_SZ + h]; s += v*v; }
    red[t] = s; __syncthreads();
    for (int off = 128; off > 0; off >>= 1) {
        if (t < off) red[t] += red[t + off];
        __syncthreads();
    }
    const float inv = 1.0f / sqrtf(red[0]);
    for (int h = t; h < H_SZ; h += 256) qn[b*H_SZ + h] = q[b*H_SZ + h] * inv;
}

// ---- kernel 2: tiled f32 GEMM (cos_sim) + fused histogram -------------------
// Tile: all 128 b rows x 64 k cols per block. 256 threads, 8b x 4k micro-tile.
// hist[row][key] packs: lo16 = negative count, hi16 = positive count.
__global__ __launch_bounds__(256) void gemm_hist_kernel(
    const float* __restrict__ qn, const float* __restrict__ fq,
    const int* __restrict__ lq, const int* __restrict__ lk,
    unsigned* __restrict__ hist)
{
    __shared__ float qs[32][128];   // [h][b]
    __shared__ float fs[32][64];    // [h][k]
    const int tid = threadIdx.x;
    const int k_base = blockIdx.x * 64;
    const int tx = tid & 15;        // k group: k0 = tx*4
    const int ty = tid >> 4;        // b group: b0 = ty*8
    float acc[8][4];
#pragma unroll
    for (int i = 0; i < 8; i++)
#pragma unroll
        for (int j = 0; j < 4; j++) acc[i][j] = 0.f;

    for (int h0 = 0; h0 < H_SZ; h0 += 32) {
        // stage q chunk: 128 x 32 floats (transposed into [h][b])
#pragma unroll
        for (int it = 0; it < 4; ++it) {
            int lin = it*256 + tid;         // 0..1023
            int b  = lin >> 3;
            int h4 = lin & 7;
            const float4 v = *(const float4*)(qn + (size_t)b*H_SZ + h0 + h4*4);
            qs[h4*4+0][b] = v.x; qs[h4*4+1][b] = v.y;
            qs[h4*4+2][b] = v.z; qs[h4*4+3][b] = v.w;
        }
        // stage F chunk: 64 x 32 floats (transposed into [h][k])
#pragma unroll
        for (int it = 0; it < 2; ++it) {
            int lin = it*256 + tid;         // 0..511
            int k  = lin >> 3;
            int h4 = lin & 7;
            const float4 v = *(const float4*)(fq + (size_t)(k_base + k)*H_SZ + h0 + h4*4);
            fs[h4*4+0][k] = v.x; fs[h4*4+1][k] = v.y;
            fs[h4*4+2][k] = v.z; fs[h4*4+3][k] = v.w;
        }
        __syncthreads();
        for (int hh = 0; hh < 32; ++hh) {
            float fb[4], qa[8];
            *(float4*)fb     = *(const float4*)&fs[hh][tx*4];
            *(float4*)qa     = *(const float4*)&qs[hh][ty*8];
            *(float4*)(qa+4) = *(const float4*)&qs[hh][ty*8+4];
#pragma unroll
            for (int i = 0; i < 8; i++)
#pragma unroll
                for (int j = 0; j < 4; j++)
                    acc[i][j] = fmaf(qa[i], fb[j], acc[i][j]);
        }
        __syncthreads();
    }

    // epilogue: histogram
    int lb[8];
#pragma unroll
    for (int i = 0; i < 8; i++) lb[i] = lq[ty*8 + i];
#pragma unroll
    for (int j = 0; j < 4; j++) {
        const int kk  = k_base + tx*4 + j;
        const int lkv = lk[kk];
#pragma unroll
        for (int i = 0; i < 8; i++) {
            const unsigned key = f32_key(acc[i][j]);
            const unsigned inc = (lb[i] == lkv) ? 0x10000u : 1u;
            atomicAdd(&hist[(size_t)(ty*8 + i)*NBINS + key], inc);
        }
    }
}

// ---- block-wide exclusive scan of (neg, all) pairs, thread order ------------
__device__ __forceinline__ void block_excl_scan_pair(
    int t, unsigned vneg, unsigned vall,
    unsigned* sneg, unsigned* sall, unsigned& eneg, unsigned& eall)
{
    sneg[t] = vneg; sall[t] = vall; __syncthreads();
    for (int off = 1; off < 256; off <<= 1) {
        unsigned a = 0, b = 0;
        if (t >= off) { a = sneg[t - off]; b = sall[t - off]; }
        __syncthreads();
        if (t >= off) { sneg[t] += a; sall[t] += b; }
        __syncthreads();
    }
    eneg = sneg[t] - vneg; eall = sall[t] - vall;
}

// ---- kernel 3: per-row chunk sums + exclusive scan (descending key order) ---
// chunk t covers keys [NBINS-256*(t+1), NBINS-256*t)
__global__ __launch_bounds__(256) void scan_kernel(
    const unsigned* __restrict__ hist, unsigned* __restrict__ offs)
{
    __shared__ unsigned sneg[256], sall[256];
    const int row = blockIdx.x, t = threadIdx.x;
    const unsigned base = NBINS - 256u*(t + 1);
    const uint4* p = (const uint4*)(hist + (size_t)row*NBINS + base);
    unsigned n = 0, a = 0;
    for (int i = 0; i < 64; ++i) {
        uint4 v = p[i];
        n += (v.x & 0xFFFFu) + (v.y & 0xFFFFu) + (v.z & 0xFFFFu) + (v.w & 0xFFFFu);
        a += (v.x >> 16)     + (v.y >> 16)     + (v.z >> 16)     + (v.w >> 16);
    }
    a += n;   // all = neg + pos
    unsigned eneg, eall;
    block_excl_scan_pair(t, n, a, sneg, sall, eneg, eall);
    offs[((size_t)row*256 + t)*2 + 0] = eneg;
    offs[((size_t)row*256 + t)*2 + 1] = eall;
}

// ---- kernel 4: emission (counting-sort decode + top-5 + 5x row repeat) ------
__global__ __launch_bounds__(256) void emit_kernel(
    const unsigned* __restrict__ hist, const unsigned* __restrict__ offs,
    float* __restrict__ out)
{
    __shared__ unsigned sneg[256], sall[256];
    const int c = blockIdx.x;       // chunk (0 = highest keys)
    const int row = blockIdx.y;
    const int t = threadIdx.x;
    const unsigned key = 65535u - (unsigned)(c*256 + t);
    const unsigned w   = hist[(size_t)row*NBINS + key];
    const unsigned neg = w & 0xFFFFu;
    const unsigned all = neg + (w >> 16);
    unsigned eneg, eall;
    block_excl_scan_pair(t, neg, all, sneg, sall, eneg, eall);
    const unsigned bn = offs[((size_t)row*256 + c)*2 + 0] + eneg;  // global neg rank
    const unsigned ba = offs[((size_t)row*256 + c)*2 + 1] + eall;  // global all rank
    const float val = key_val(key) * INV_T;

    // pos_sample: ranks 0..4 over ALL sims -> col 0 of rows row*5 + rank
    if (ba < TOPK && all > 0) {
        const unsigned end = (ba + all < TOPK) ? (ba + all) : TOPK;
        for (unsigned r = ba; r < end; ++r)
            out[((size_t)row*TOPK + r)*OUTC] = val;
    }
    // negatives: run of `neg` copies at cols [1+bn, 1+bn+neg), replicated 5 rows
    float* orow = out + (size_t)row*TOPK*OUTC;
    for (unsigned j = 0; j < neg; ++j) {
        const size_t col = 1 + (size_t)bn + j;
        orow[col]            = val;
        orow[OUTC   + col]   = val;
        orow[2*OUTC + col]   = val;
        orow[3*OUTC + col]   = val;
        orow[4*OUTC + col]   = val;
    }
}

extern "C" void kernel_launch(void* const* d_in, const int* in_sizes, int n_in,
                              void* d_out, int out_size, void* d_ws, size_t ws_size,
                              hipStream_t stream)
{
    (void)in_sizes; (void)n_in; (void)out_size; (void)ws_size;
    const float* liner_q = (const float*)d_in[0];
    const float* fq      = (const float*)d_in[1];
    const int*   lq      = (const int*)d_in[2];
    const int*   lk      = (const int*)d_in[3];
    float* out = (float*)d_out;

    char* ws = (char*)d_ws;
    float*    qn   = (float*)ws;                          // 128*768*4   = 393,216 B
    unsigned* offs = (unsigned*)(ws + 393216);            // 128*256*2*4 = 262,144 B
    unsigned* hist = (unsigned*)(ws + 655360);            // 128*65536*4 = 33,554,432 B

    hipMemsetAsync(hist, 0, (size_t)B_SZ*NBINS*sizeof(unsigned), stream);
    norm_kernel<<<B_SZ, 256, 0, stream>>>(liner_q, qn);
    gemm_hist_kernel<<<K_SZ/64, 256, 0, stream>>>(qn, fq, lq, lk, hist);
    scan_kernel<<<B_SZ, 256, 0, stream>>>(hist, offs);
    emit_kernel<<<dim3(256, B_SZ), 256, 0, stream>>>(hist, offs, out);
}

// Round 7
// 817.430 us; speedup vs baseline: 1.5920x; 1.5920x over previous
//
#include <hip/hip_runtime.h>
#include <hip/hip_bf16.h>

// Problem constants (match reference)
#define B_SZ 128
#define K_SZ 65536
#define H_SZ 768
#define TOPK 5
#define NEG_MIN 64512
#define OUTC 64513            // NEG_MIN + 1
#define NBINS 65536
#define INV_T (1.0f/0.07f)

typedef __attribute__((ext_vector_type(8))) short short8;
typedef __attribute__((ext_vector_type(4))) float f32x4;

// ---- bf16 helpers -----------------------------------------------------------
__device__ __forceinline__ unsigned short f32_bf16(float v) {
    unsigned u = __float_as_uint(v);
    unsigned r = ((u >> 16) & 1u) + 0x7FFFu;
    return (unsigned short)((u + r) >> 16);              // RNE bf16 bits
}
// sortable 16-bit key <-> bf16 value (ascending key == ascending value)
__device__ __forceinline__ unsigned f32_key(float v) {
    unsigned u = __float_as_uint(v);
    unsigned r = ((u >> 16) & 1u) + 0x7FFFu;
    unsigned b = (u + r) >> 16;
    return (b & 0x8000u) ? (0xFFFFu & ~b) : (b | 0x8000u);
}
__device__ __forceinline__ float key_val(unsigned key) {
    unsigned b = (key & 0x8000u) ? (key ^ 0x8000u) : (0xFFFFu & ~key);
    return __uint_as_float(b << 16);
}

// ---- kernel 1: l2-normalize q -> bf16 --------------------------------------
__global__ __launch_bounds__(256) void norm_kernel(const float* __restrict__ q,
                                                   unsigned short* __restrict__ qn) {
    __shared__ float red[256];
    const int b = blockIdx.x, t = threadIdx.x;
    float s = 0.f;
    for (int h = t; h < H_SZ; h += 256) { float v = q[b*H_SZ + h]; s += v*v; }
    red[t] = s; __syncthreads();
    for (int off = 128; off > 0; off >>= 1) {
        if (t < off) red[t] += red[t + off];
        __syncthreads();
    }
    const float inv = 1.0f / sqrtf(red[0]);
    for (int h = t; h < H_SZ; h += 256) qn[b*H_SZ + h] = f32_bf16(q[b*H_SZ + h] * inv);
}

// ---- kernel 2: bf16 MFMA GEMM (cos_sim) + fused histogram -------------------
// Block tile: 128 queue rows x 128 batch cols. 4 waves; wave w owns queue rows
// [w*32, w*32+32). K staged in 32-chunks, f32->bf16 converted into padded LDS.
// hist[batch][key] packs: lo16 = negative count, hi16 = positive count.
__global__ __launch_bounds__(256) void gemm_hist_kernel(
    const unsigned short* __restrict__ qn, const float* __restrict__ fq,
    const int* __restrict__ lq, const int* __restrict__ lk,
    unsigned* __restrict__ hist)
{
    __shared__ unsigned short Fs[128][40];   // [queue_local][k], +8 pad (stride 80 B)
    __shared__ unsigned short Qs[128][40];   // [batch][k]
    const int tid  = threadIdx.x;
    const int lane = tid & 63;
    const int w    = tid >> 6;
    const int k_base = blockIdx.x * 128;

    f32x4 acc[2][8];
#pragma unroll
    for (int mg = 0; mg < 2; ++mg)
#pragma unroll
        for (int bg = 0; bg < 8; ++bg) acc[mg][bg] = (f32x4){0.f, 0.f, 0.f, 0.f};

    for (int kc = 0; kc < H_SZ/32; ++kc) {
        const int c0 = kc * 32;
        __syncthreads();
        // stage F chunk: 128 rows x 32 k (f32 -> bf16); 1024 tasks = 128 rows x 8 groups of 4
#pragma unroll
        for (int it = 0; it < 4; ++it) {
            const int task = it*256 + tid;        // 0..1023
            const int r = task >> 3, q = task & 7;
            const float4 v = *(const float4*)(fq + (size_t)(k_base + r)*H_SZ + c0 + q*4);
            ushort4 b4;
            b4.x = f32_bf16(v.x); b4.y = f32_bf16(v.y);
            b4.z = f32_bf16(v.z); b4.w = f32_bf16(v.w);
            *(ushort4*)(&Fs[r][q*4]) = b4;
        }
        // stage Q chunk: 128 rows x 32 k (already bf16); 512 tasks = 128 rows x 4 groups of 8
#pragma unroll
        for (int it = 0; it < 2; ++it) {
            const int task = it*256 + tid;        // 0..511
            const int r = task >> 2, h = task & 3;   // FIX: was >>1 / &1 (OOB + half-staged)
            const uint4 v = *(const uint4*)(qn + (size_t)r*H_SZ + c0 + h*8);
            *(uint4*)(&Qs[r][h*8]) = v;
        }
        __syncthreads();
        // fragments: A = F (16 rows x 32 k), B = Q^T (32 k x 16 batch)
        const int ko = (lane >> 4) * 8;
        short8 a[2], bq[8];
        a[0] = *(const short8*)(&Fs[w*32      + (lane & 15)][ko]);
        a[1] = *(const short8*)(&Fs[w*32 + 16 + (lane & 15)][ko]);
#pragma unroll
        for (int bg = 0; bg < 8; ++bg)
            bq[bg] = *(const short8*)(&Qs[bg*16 + (lane & 15)][ko]);
#pragma unroll
        for (int mg = 0; mg < 2; ++mg)
#pragma unroll
            for (int bg = 0; bg < 8; ++bg)
                acc[mg][bg] = __builtin_amdgcn_mfma_f32_16x16x32_bf16(
                    a[mg], bq[bg], acc[mg][bg], 0, 0, 0);
    }

    // epilogue: histogram. D mapping: col = lane&15 (batch), row = (lane>>4)*4+reg.
    const int col  = lane & 15;
    const int rgrp = (lane >> 4) * 4;
    int lb[8];
#pragma unroll
    for (int bg = 0; bg < 8; ++bg) lb[bg] = lq[bg*16 + col];
    int lkv[2][4];
#pragma unroll
    for (int mg = 0; mg < 2; ++mg)
#pragma unroll
        for (int r = 0; r < 4; ++r)
            lkv[mg][r] = lk[k_base + w*32 + mg*16 + rgrp + r];
#pragma unroll
    for (int mg = 0; mg < 2; ++mg)
#pragma unroll
        for (int bg = 0; bg < 8; ++bg)
#pragma unroll
            for (int r = 0; r < 4; ++r) {
                const unsigned key = f32_key(acc[mg][bg][r]);
                const unsigned inc = (lb[bg] == lkv[mg][r]) ? 0x10000u : 1u;
                atomicAdd(&hist[(size_t)(bg*16 + col)*NBINS + key], inc);
            }
}

// ---- block-wide exclusive scan of (neg, all) pairs --------------------------
__device__ __forceinline__ void block_excl_scan_pair(
    int t, unsigned vneg, unsigned vall,
    unsigned* sneg, unsigned* sall, unsigned& eneg, unsigned& eall)
{
    sneg[t] = vneg; sall[t] = vall; __syncthreads();
    for (int off = 1; off < 256; off <<= 1) {
        unsigned a = 0, b = 0;
        if (t >= off) { a = sneg[t - off]; b = sall[t - off]; }
        __syncthreads();
        if (t >= off) { sneg[t] += a; sall[t] += b; }
        __syncthreads();
    }
    eneg = sneg[t] - vneg; eall = sall[t] - vall;
}

// ---- kernel 3: per-row chunk sums + exclusive scan (descending key order) ---
__global__ __launch_bounds__(256) void scan_kernel(
    const unsigned* __restrict__ hist, unsigned* __restrict__ offs)
{
    __shared__ unsigned sneg[256], sall[256];
    const int row = blockIdx.x, t = threadIdx.x;
    const unsigned base = NBINS - 256u*(t + 1);
    const uint4* p = (const uint4*)(hist + (size_t)row*NBINS + base);
    unsigned n = 0, a = 0;
    for (int i = 0; i < 64; ++i) {
        uint4 v = p[i];
        n += (v.x & 0xFFFFu) + (v.y & 0xFFFFu) + (v.z & 0xFFFFu) + (v.w & 0xFFFFu);
        a += (v.x >> 16)     + (v.y >> 16)     + (v.z >> 16)     + (v.w >> 16);
    }
    a += n;   // all = neg + pos
    unsigned eneg, eall;
    block_excl_scan_pair(t, n, a, sneg, sall, eneg, eall);
    offs[((size_t)row*256 + t)*2 + 0] = eneg;
    offs[((size_t)row*256 + t)*2 + 1] = eall;
}

// ---- kernel 4: emission — rank-decode, coalesced ----------------------------
// Block = (chunk c, row). Thread = one bin for the scan; then all 256 threads
// cooperatively write the chunk's S negative elements with coalesced stores,
// finding each element's bin via binary search over the LDS prefix.
__global__ __launch_bounds__(256) void emit_kernel(
    const unsigned* __restrict__ hist, const unsigned* __restrict__ offs,
    float* __restrict__ out)
{
    __shared__ unsigned sneg[256], sall[256];
    __shared__ unsigned cum[257];
    __shared__ float vals[256];
    const int c = blockIdx.x, row = blockIdx.y, t = threadIdx.x;
    const unsigned key = 65535u - (unsigned)(c*256 + t);
    const unsigned w   = hist[(size_t)row*NBINS + key];
    const unsigned neg = w & 0xFFFFu;
    const unsigned all = neg + (w >> 16);
    unsigned eneg, eall;
    block_excl_scan_pair(t, neg, all, sneg, sall, eneg, eall);
    const float val = key_val(key) * INV_T;
    vals[t] = val;
    cum[t + 1] = eneg + neg;
    if (t == 0) cum[0] = 0;

    // pos_sample: ranks 0..4 over ALL sims -> col 0 of rows row*5 + rank
    const unsigned ba = offs[((size_t)row*256 + c)*2 + 1] + eall;
    if (ba < TOPK && all > 0) {
        const unsigned end = (ba + all < TOPK) ? (ba + all) : TOPK;
        for (unsigned r = ba; r < end; ++r)
            out[((size_t)row*TOPK + r)*OUTC] = val;
    }
    __syncthreads();

    const unsigned S    = cum[256];
    const unsigned base = offs[((size_t)row*256 + c)*2 + 0];
    float* orow = out + (size_t)row*TOPK*OUTC + 1 + base;
    for (unsigned e = t; e < S; e += 256) {
        unsigned lo = 0, hi = 255;
#pragma unroll
        for (int i = 0; i < 8; ++i) {
            const unsigned mid = (lo + hi) >> 1;
            if (cum[mid + 1] > e) hi = mid; else lo = mid + 1;
        }
        const float v = vals[lo];
        orow[e]          = v;
        orow[OUTC   + e] = v;
        orow[2*OUTC + e] = v;
        orow[3*OUTC + e] = v;
        orow[4*OUTC + e] = v;
    }
}

extern "C" void kernel_launch(void* const* d_in, const int* in_sizes, int n_in,
                              void* d_out, int out_size, void* d_ws, size_t ws_size,
                              hipStream_t stream)
{
    (void)in_sizes; (void)n_in; (void)out_size; (void)ws_size;
    const float* liner_q = (const float*)d_in[0];
    const float* fq      = (const float*)d_in[1];
    const int*   lq      = (const int*)d_in[2];
    const int*   lk      = (const int*)d_in[3];
    float* out = (float*)d_out;

    char* ws = (char*)d_ws;
    unsigned short* qn   = (unsigned short*)ws;           // 128*768*2   = 196,608 B
    unsigned*       offs = (unsigned*)(ws + 196608);      // 128*256*2*4 = 262,144 B
    unsigned*       hist = (unsigned*)(ws + 458752);      // 128*65536*4 = 33,554,432 B

    hipMemsetAsync(hist, 0, (size_t)B_SZ*NBINS*sizeof(unsigned), stream);
    norm_kernel<<<B_SZ, 256, 0, stream>>>(liner_q, qn);
    gemm_hist_kernel<<<K_SZ/128, 256, 0, stream>>>(qn, fq, lq, lk, hist);
    scan_kernel<<<B_SZ, 256, 0, stream>>>(hist, offs);
    emit_kernel<<<dim3(256, B_SZ), 256, 0, stream>>>(hist, offs, out);
}

// Round 8
// 548.652 us; speedup vs baseline: 2.3719x; 1.4899x over previous
//
#include <hip/hip_runtime.h>
#include <hip/hip_bf16.h>

#define B_SZ 128
#define K_SZ 65536
#define H_SZ 768
#define TOPK 5
#define NEG_MIN 64512
#define OUTC 64513            // NEG_MIN + 1
#define NBINS 65536
#define INV_T (1.0f/0.07f)

typedef __attribute__((ext_vector_type(8))) short short8;
typedef __attribute__((ext_vector_type(4))) float f32x4;

// ---- bf16 / sortable-key helpers -------------------------------------------
__device__ __forceinline__ unsigned short f32_bf16(float v) {
    unsigned u = __float_as_uint(v);
    unsigned r = ((u >> 16) & 1u) + 0x7FFFu;
    return (unsigned short)((u + r) >> 16);              // RNE bf16 bits
}
__device__ __forceinline__ unsigned f32_key(float v) {
    unsigned u = __float_as_uint(v);
    unsigned r = ((u >> 16) & 1u) + 0x7FFFu;
    unsigned b = (u + r) >> 16;
    return (b & 0x8000u) ? (0xFFFFu & ~b) : (b | 0x8000u);
}
__device__ __forceinline__ float key_val(unsigned key) {
    unsigned b = (key & 0x8000u) ? (key ^ 0x8000u) : (0xFFFFu & ~key);
    return __uint_as_float(b << 16);
}

// ---- kernel 1: l2-normalize q -> bf16 --------------------------------------
__global__ __launch_bounds__(256) void norm_kernel(const float* __restrict__ q,
                                                   unsigned short* __restrict__ qn) {
    __shared__ float red[256];
    const int b = blockIdx.x, t = threadIdx.x;
    float s = 0.f;
    for (int h = t; h < H_SZ; h += 256) { float v = q[b*H_SZ + h]; s += v*v; }
    red[t] = s; __syncthreads();
    for (int off = 128; off > 0; off >>= 1) {
        if (t < off) red[t] += red[t + off];
        __syncthreads();
    }
    const float inv = 1.0f / sqrtf(red[0]);
    for (int h = t; h < H_SZ; h += 256) qn[b*H_SZ + h] = f32_bf16(q[b*H_SZ + h] * inv);
}

// ---- kernel 2: bf16 MFMA GEMM -> u16 sortable keys --------------------------
// Keys for batch row b live in the FIRST HALF of hist row b (aliased; the
// hist kernel consumes them before overwriting the row).
__global__ __launch_bounds__(256) void gemm_key_kernel(
    const unsigned short* __restrict__ qn, const float* __restrict__ fq,
    unsigned* __restrict__ hist)
{
    __shared__ unsigned short Fs[128][40];
    __shared__ unsigned short Qs[128][40];
    const int tid  = threadIdx.x;
    const int lane = tid & 63;
    const int w    = tid >> 6;
    const int k_base = blockIdx.x * 128;

    f32x4 acc[2][8];
#pragma unroll
    for (int mg = 0; mg < 2; ++mg)
#pragma unroll
        for (int bg = 0; bg < 8; ++bg) acc[mg][bg] = (f32x4){0.f, 0.f, 0.f, 0.f};

    for (int kc = 0; kc < H_SZ/32; ++kc) {
        const int c0 = kc * 32;
        __syncthreads();
#pragma unroll
        for (int it = 0; it < 4; ++it) {
            const int task = it*256 + tid;
            const int r = task >> 3, q = task & 7;
            const float4 v = *(const float4*)(fq + (size_t)(k_base + r)*H_SZ + c0 + q*4);
            ushort4 b4;
            b4.x = f32_bf16(v.x); b4.y = f32_bf16(v.y);
            b4.z = f32_bf16(v.z); b4.w = f32_bf16(v.w);
            *(ushort4*)(&Fs[r][q*4]) = b4;
        }
#pragma unroll
        for (int it = 0; it < 2; ++it) {
            const int task = it*256 + tid;
            const int r = task >> 2, h = task & 3;
            const uint4 v = *(const uint4*)(qn + (size_t)r*H_SZ + c0 + h*8);
            *(uint4*)(&Qs[r][h*8]) = v;
        }
        __syncthreads();
        const int ko = (lane >> 4) * 8;
        short8 a[2], bq[8];
        a[0] = *(const short8*)(&Fs[w*32      + (lane & 15)][ko]);
        a[1] = *(const short8*)(&Fs[w*32 + 16 + (lane & 15)][ko]);
#pragma unroll
        for (int bg = 0; bg < 8; ++bg)
            bq[bg] = *(const short8*)(&Qs[bg*16 + (lane & 15)][ko]);
#pragma unroll
        for (int mg = 0; mg < 2; ++mg)
#pragma unroll
            for (int bg = 0; bg < 8; ++bg)
                acc[mg][bg] = __builtin_amdgcn_mfma_f32_16x16x32_bf16(
                    a[mg], bq[bg], acc[mg][bg], 0, 0, 0);
    }

    // epilogue: D col = lane&15 (batch), row = (lane>>4)*4 + reg (queue)
    const int col  = lane & 15;
    const int rgrp = (lane >> 4) * 4;
#pragma unroll
    for (int mg = 0; mg < 2; ++mg)
#pragma unroll
        for (int bg = 0; bg < 8; ++bg) {
            ushort4 kk;
            kk.x = (unsigned short)f32_key(acc[mg][bg][0]);
            kk.y = (unsigned short)f32_key(acc[mg][bg][1]);
            kk.z = (unsigned short)f32_key(acc[mg][bg][2]);
            kk.w = (unsigned short)f32_key(acc[mg][bg][3]);
            unsigned short* dst = (unsigned short*)(hist + (size_t)(bg*16 + col)*NBINS)
                                  + (k_base + w*32 + mg*16 + rgrp);
            *(ushort4*)dst = kk;
        }
}

// ---- kernel 3: per-row histogram via 128KB LDS ------------------------------
// Reads the row's 65536 keys (aliased in hist row), bins into packed u16 LDS
// counters, flushes unpacked (all-counts in lo16), then converts positives:
// atomicAdd(word, 0xFFFF) == {lo16 -= 1, hi16 += 1} -> (neg, pos) packed.
__global__ __launch_bounds__(256) void hist_kernel(
    const int* __restrict__ lq, const int* __restrict__ lk,
    unsigned* __restrict__ hist)
{
    __shared__ unsigned packed[NBINS/2];      // 131072 B
    __shared__ unsigned short plist[1152];
    __shared__ unsigned pcount;
    const int row = blockIdx.x, t = threadIdx.x;
#pragma unroll
    for (int i = 0; i < 128; ++i) packed[i*256 + t] = 0;
    if (t == 0) pcount = 0;
    const int myl = lq[row];
    unsigned* hrow = hist + (size_t)row*NBINS;
    const uint4* kp = (const uint4*)hrow;     // keys: 8192 uint4 (8 keys each)
    __syncthreads();

    for (int it = 0; it < 32; ++it) {
        const int idx = it*256 + t;
        const uint4 kv = kp[idx];
        const int4 l0 = ((const int4*)lk)[idx*2];
        const int4 l1 = ((const int4*)lk)[idx*2 + 1];
        unsigned ks[8] = { kv.x & 0xFFFFu, kv.x >> 16, kv.y & 0xFFFFu, kv.y >> 16,
                           kv.z & 0xFFFFu, kv.z >> 16, kv.w & 0xFFFFu, kv.w >> 16 };
        int ls[8] = { l0.x, l0.y, l0.z, l0.w, l1.x, l1.y, l1.z, l1.w };
#pragma unroll
        for (int j = 0; j < 8; ++j) {
            atomicAdd(&packed[ks[j] >> 1], (ks[j] & 1u) ? 0x10000u : 1u);
            if (ls[j] == myl) {
                unsigned p = atomicAdd(&pcount, 1u);
                if (p < 1152) plist[p] = (unsigned short)ks[j];
            }
        }
    }
    __syncthreads();
    // flush: 8192 packed uint4 -> 16384 output uint4 (all-counts, hi16 = 0)
    for (int i = 0; i < 32; ++i) {
        const int idx = i*256 + t;
        const uint4 pw = ((const uint4*)packed)[idx];
        uint4 o0, o1;
        o0.x = pw.x & 0xFFFFu; o0.y = pw.x >> 16; o0.z = pw.y & 0xFFFFu; o0.w = pw.y >> 16;
        o1.x = pw.z & 0xFFFFu; o1.y = pw.z >> 16; o1.z = pw.w & 0xFFFFu; o1.w = pw.w >> 16;
        ((uint4*)hrow)[idx*2]     = o0;
        ((uint4*)hrow)[idx*2 + 1] = o1;
    }
    __syncthreads();
    const unsigned np = pcount < 1152u ? pcount : 1152u;
    for (unsigned p = t; p < np; p += 256)
        atomicAdd(&hrow[plist[p]], 0xFFFFu);   // neg -= 1, pos += 1
}

// ---- wave-level inclusive scan helpers --------------------------------------
__device__ __forceinline__ void wave_scan2(int lane, unsigned& sn, unsigned& sa) {
#pragma unroll
    for (int off = 1; off < 64; off <<= 1) {
        unsigned un = __shfl_up(sn, off, 64);
        unsigned ua = __shfl_up(sa, off, 64);
        if (lane >= off) { sn += un; sa += ua; }
    }
}

// ---- kernel 4: per-row chunk sums + exclusive scan (descending key order) ---
__global__ __launch_bounds__(256) void scan_kernel(
    const unsigned* __restrict__ hist, unsigned* __restrict__ offs)
{
    __shared__ unsigned cn[256], ca[256];
    __shared__ unsigned wn[4], wa[4];
    const int row = blockIdx.x, t = threadIdx.x;
    const int wv = t >> 6, lane = t & 63;
    const uint4* hp = (const uint4*)(hist + (size_t)row*NBINS);
    // wave (i, wv) reduces ascending chunk cb = i*4 + wv (256 bins, coalesced)
    for (int i = 0; i < 64; ++i) {
        const uint4 v = hp[i*256 + t];
        unsigned n = (v.x & 0xFFFFu) + (v.y & 0xFFFFu) + (v.z & 0xFFFFu) + (v.w & 0xFFFFu);
        unsigned a = (v.x >> 16)     + (v.y >> 16)     + (v.z >> 16)     + (v.w >> 16);
#pragma unroll
        for (int off = 1; off < 64; off <<= 1) {
            n += __shfl_xor(n, off, 64);
            a += __shfl_xor(a, off, 64);
        }
        if (lane == 0) { cn[i*4 + wv] = n; ca[i*4 + wv] = a; }
    }
    __syncthreads();
    // thread t = DESC chunk index -> ascending chunk 255-t
    const unsigned vn = cn[255 - t];
    const unsigned va = ca[255 - t] + vn;          // all = neg + pos
    unsigned sn = vn, sa = va;
    wave_scan2(lane, sn, sa);
    if (lane == 63) { wn[wv] = sn; wa[wv] = sa; }
    __syncthreads();
    unsigned pn = 0, pa = 0;
    for (int i = 0; i < wv; ++i) { pn += wn[i]; pa += wa[i]; }
    offs[((size_t)row*256 + t)*2 + 0] = pn + sn - vn;   // exclusive neg
    offs[((size_t)row*256 + t)*2 + 1] = pa + sa - va;   // exclusive all
}

// ---- kernel 5: emission — rank-decode, coalesced, shfl scan -----------------
__global__ __launch_bounds__(256) void emit_kernel(
    const unsigned* __restrict__ hist, const unsigned* __restrict__ offs,
    float* __restrict__ out)
{
    __shared__ unsigned wn[4], wa[4];
    __shared__ unsigned cum[257];
    __shared__ float vals[256];
    const int c = blockIdx.x, row = blockIdx.y, t = threadIdx.x;
    const int wv = t >> 6, lane = t & 63;
    const unsigned key = 65535u - (unsigned)(c*256 + t);
    const unsigned w   = hist[(size_t)row*NBINS + key];
    const unsigned neg = w & 0xFFFFu;
    const unsigned all = neg + (w >> 16);
    unsigned sn = neg, sa = all;
    wave_scan2(lane, sn, sa);
    if (lane == 63) { wn[wv] = sn; wa[wv] = sa; }
    __syncthreads();
    unsigned pn = 0, pa = 0;
    for (int i = 0; i < wv; ++i) { pn += wn[i]; pa += wa[i]; }
    const unsigned eneg = pn + sn - neg;           // exclusive within chunk
    const unsigned eall = pa + sa - all;
    const float val = key_val(key) * INV_T;
    vals[t] = val;
    cum[t + 1] = pn + sn;                          // inclusive neg prefix
    if (t == 0) cum[0] = 0;

    // pos_sample: ranks 0..4 over ALL sims -> col 0 of rows row*5 + rank
    const unsigned ba = offs[((size_t)row*256 + c)*2 + 1] + eall;
    if (ba < TOPK && all > 0) {
        const unsigned end = (ba + all < TOPK) ? (ba + all) : TOPK;
        for (unsigned r = ba; r < end; ++r)
            out[((size_t)row*TOPK + r)*OUTC] = val;
    }
    __syncthreads();

    const unsigned S    = cum[256];
    const unsigned base = offs[((size_t)row*256 + c)*2 + 0];
    float* orow = out + (size_t)row*TOPK*OUTC + 1 + base;
    for (unsigned e = t; e < S; e += 256) {
        unsigned lo = 0, hi = 255;
#pragma unroll
        for (int i = 0; i < 8; ++i) {
            const unsigned mid = (lo + hi) >> 1;
            if (cum[mid + 1] > e) hi = mid; else lo = mid + 1;
        }
        const float v = vals[lo];
        orow[e]          = v;
        orow[OUTC   + e] = v;
        orow[2*OUTC + e] = v;
        orow[3*OUTC + e] = v;
        orow[4*OUTC + e] = v;
    }
}

extern "C" void kernel_launch(void* const* d_in, const int* in_sizes, int n_in,
                              void* d_out, int out_size, void* d_ws, size_t ws_size,
                              hipStream_t stream)
{
    (void)in_sizes; (void)n_in; (void)out_size; (void)ws_size;
    const float* liner_q = (const float*)d_in[0];
    const float* fq      = (const float*)d_in[1];
    const int*   lq      = (const int*)d_in[2];
    const int*   lk      = (const int*)d_in[3];
    float* out = (float*)d_out;

    char* ws = (char*)d_ws;
    unsigned short* qn   = (unsigned short*)ws;           // 196,608 B
    unsigned*       offs = (unsigned*)(ws + 196608);      // 262,144 B
    unsigned*       hist = (unsigned*)(ws + 458752);      // 33,554,432 B (keys aliased)

    norm_kernel<<<B_SZ, 256, 0, stream>>>(liner_q, qn);
    gemm_key_kernel<<<K_SZ/128, 256, 0, stream>>>(qn, fq, hist);
    hist_kernel<<<B_SZ, 256, 0, stream>>>(lq, lk, hist);
    scan_kernel<<<B_SZ, 256, 0, stream>>>(hist, offs);
    emit_kernel<<<dim3(256, B_SZ), 256, 0, stream>>>(hist, offs, out);
}